// Round 1
// baseline (124.400 us; speedup 1.0000x reference)
//
#include <hip/hip_runtime.h>

#define B_ 16
#define QN 256
#define KN 256
#define DN 256
#define HN 256

// 2*log2(e): exp2(x*C) = e^{2x}
__device__ __constant__ float kTwoLog2e = 2.8853900817779268f;
#define LOG2E 1.4426950408889634f

// ---------------- Kernel A: Y[r][h] = (sum_d X[r][d]*W[d][h]) * scale ----------------
__global__ __launch_bounds__(256) void proj_kernel(const float* __restrict__ X,
                                                   const float* __restrict__ W,
                                                   float* __restrict__ Y,
                                                   float scale) {
    __shared__ float row_lds[16][DN];
    const int h = threadIdx.x;
    const int row0 = blockIdx.x * 16;

    // stage 16 contiguous rows (16*256 floats = 1024 float4)
    const float4* src = (const float4*)(X + (size_t)row0 * DN);
    float4* dst = (float4*)&row_lds[0][0];
#pragma unroll
    for (int i = 0; i < 4; ++i) dst[threadIdx.x + 256 * i] = src[threadIdx.x + 256 * i];
    __syncthreads();

    float acc[16];
#pragma unroll
    for (int r = 0; r < 16; ++r) acc[r] = 0.f;

    for (int d0 = 0; d0 < DN; d0 += 4) {
        float w0 = W[(d0 + 0) * HN + h];
        float w1 = W[(d0 + 1) * HN + h];
        float w2 = W[(d0 + 2) * HN + h];
        float w3 = W[(d0 + 3) * HN + h];
#pragma unroll
        for (int r = 0; r < 16; ++r) {
            float4 x = *(const float4*)&row_lds[r][d0];
            acc[r] = fmaf(x.x, w0, acc[r]);
            acc[r] = fmaf(x.y, w1, acc[r]);
            acc[r] = fmaf(x.z, w2, acc[r]);
            acc[r] = fmaf(x.w, w3, acc[r]);
        }
    }
#pragma unroll
    for (int r = 0; r < 16; ++r)
        Y[(size_t)(row0 + r) * HN + h] = acc[r] * scale;
}

// ------------- Kernel B: ACC[b][q][k] = sum_h wv[h] * rcp(1 + exp2(qs+ks)) -------------
// (true score = Wsum - 2*ACC; Wsum constant per row -> softmax-invariant)
__global__ __launch_bounds__(256) void score_kernel(const float* __restrict__ QS,
                                                    const float* __restrict__ KS,
                                                    const float* __restrict__ wv,
                                                    const int* __restrict__ lens,
                                                    float* __restrict__ ACC) {
    const int b = blockIdx.z;
    const int k0 = blockIdx.x * 16;
    const int q0 = blockIdx.y * 16;
    const int len = lens[b];
    if (k0 >= len) return;  // whole tile masked out -> never read downstream

    __shared__ float qs[16][260];   // pad to 260 floats: 2-way bank aliasing only (free)
    __shared__ float ks[16][260];
    __shared__ float wvl[256];

    const int tid = threadIdx.x;
    const float4* qsrc = (const float4*)(QS + ((size_t)b * QN + q0) * HN);
    const float4* ksrc = (const float4*)(KS + ((size_t)b * KN + k0) * HN);
#pragma unroll
    for (int i = tid; i < 1024; i += 256) {
        int r = i >> 6, c = (i & 63) << 2;
        *(float4*)&qs[r][c] = qsrc[i];
        *(float4*)&ks[r][c] = ksrc[i];
    }
    if (tid < 64) *(float4*)&wvl[tid << 2] = ((const float4*)wv)[tid];
    __syncthreads();

    const int q = tid >> 4, k = tid & 15;
    const float* qrow = &qs[q][0];
    const float* krow = &ks[k][0];
    float acc = 0.f;
#pragma unroll 4
    for (int h = 0; h < HN; h += 4) {
        float4 a = *(const float4*)&qrow[h];
        float4 c4 = *(const float4*)&krow[h];
        float4 w4 = *(const float4*)&wvl[h];
        float e0 = __builtin_amdgcn_exp2f(a.x + c4.x);
        float e1 = __builtin_amdgcn_exp2f(a.y + c4.y);
        float e2 = __builtin_amdgcn_exp2f(a.z + c4.z);
        float e3 = __builtin_amdgcn_exp2f(a.w + c4.w);
        acc = fmaf(w4.x, __builtin_amdgcn_rcpf(1.f + e0), acc);
        acc = fmaf(w4.y, __builtin_amdgcn_rcpf(1.f + e1), acc);
        acc = fmaf(w4.z, __builtin_amdgcn_rcpf(1.f + e2), acc);
        acc = fmaf(w4.w, __builtin_amdgcn_rcpf(1.f + e3), acc);
    }
    ACC[((size_t)b * QN + q0 + q) * KN + k0 + k] = acc;
}

// ------------- Kernel C: masked softmax over (-2*ACC) then attn @ values -------------
__global__ __launch_bounds__(256) void softmax_pv_kernel(const float* __restrict__ ACC,
                                                         const float* __restrict__ V,
                                                         const int* __restrict__ lens,
                                                         float* __restrict__ OUT) {
    const int b = blockIdx.y;
    const int q0 = blockIdx.x * 16;
    const int len = lens[b];

    __shared__ float sl[16][256];
    const int tid = threadIdx.x;

    const float* src = ACC + ((size_t)b * QN + q0) * KN;
    for (int i = tid; i < 16 * 256; i += 256) {
        int r = i >> 8, k = i & 255;
        float v = src[r * KN + k];
        sl[r][k] = (k < len) ? (-2.f * v) : -1e6f;
    }
    __syncthreads();

    // wave-parallel row softmax: wave w handles rows w, w+4, w+8, w+12
    const int wave = tid >> 6, lane = tid & 63;
    for (int r = wave; r < 16; r += 4) {
        float x0 = sl[r][lane];
        float x1 = sl[r][lane + 64];
        float x2 = sl[r][lane + 128];
        float x3 = sl[r][lane + 192];
        float m = fmaxf(fmaxf(x0, x1), fmaxf(x2, x3));
#pragma unroll
        for (int off = 32; off; off >>= 1) m = fmaxf(m, __shfl_xor(m, off, 64));
        float p0 = __builtin_amdgcn_exp2f((x0 - m) * LOG2E);
        float p1 = __builtin_amdgcn_exp2f((x1 - m) * LOG2E);
        float p2 = __builtin_amdgcn_exp2f((x2 - m) * LOG2E);
        float p3 = __builtin_amdgcn_exp2f((x3 - m) * LOG2E);
        float s = (p0 + p1) + (p2 + p3);
#pragma unroll
        for (int off = 32; off; off >>= 1) s += __shfl_xor(s, off, 64);
        float inv = 1.f / s;
        sl[r][lane] = p0 * inv;
        sl[r][lane + 64] = p1 * inv;
        sl[r][lane + 128] = p2 * inv;
        sl[r][lane + 192] = p3 * inv;
    }
    __syncthreads();

    // PV: thread owns column d; masked attn entries are exactly 0
    const int d = tid;
    float out_acc[16];
#pragma unroll
    for (int r = 0; r < 16; ++r) out_acc[r] = 0.f;

    const float* vbase = V + (size_t)b * KN * DN + d;
    const int len4 = (len + 3) & ~3;
    for (int k = 0; k < len4; k += 4) {
        float v0 = vbase[(size_t)(k + 0) * DN];
        float v1 = vbase[(size_t)(k + 1) * DN];
        float v2 = vbase[(size_t)(k + 2) * DN];
        float v3 = vbase[(size_t)(k + 3) * DN];
#pragma unroll
        for (int r = 0; r < 16; ++r) {
            float4 a = *(const float4*)&sl[r][k];
            out_acc[r] = fmaf(a.x, v0, out_acc[r]);
            out_acc[r] = fmaf(a.y, v1, out_acc[r]);
            out_acc[r] = fmaf(a.z, v2, out_acc[r]);
            out_acc[r] = fmaf(a.w, v3, out_acc[r]);
        }
    }
    float* obase = OUT + ((size_t)b * QN + q0) * DN + d;
#pragma unroll
    for (int r = 0; r < 16; ++r) obase[(size_t)r * DN] = out_acc[r];
}

extern "C" void kernel_launch(void* const* d_in, const int* in_sizes, int n_in,
                              void* d_out, int out_size, void* d_ws, size_t ws_size,
                              hipStream_t stream) {
    const float* queries = (const float*)d_in[0];
    const float* keys    = (const float*)d_in[1];
    const float* values  = (const float*)d_in[2];
    const int*   lens    = (const int*)d_in[3];
    const float* Wq      = (const float*)d_in[4];
    const float* Wk      = (const float*)d_in[5];
    const float* wv      = (const float*)d_in[6];
    float* out = (float*)d_out;

    float* qs  = (float*)d_ws;                       // [B,Q,H]  4 MB
    float* ks  = qs + (size_t)B_ * QN * HN;          // [B,K,H]  4 MB
    float* acc = ks + (size_t)B_ * KN * HN;          // [B,Q,K]  4 MB

    const float scale = 2.8853900817779268f;  // 2*log2(e)

    proj_kernel<<<B_ * QN / 16, 256, 0, stream>>>(queries, Wq, qs, scale);
    proj_kernel<<<B_ * KN / 16, 256, 0, stream>>>(keys, Wk, ks, scale);

    dim3 gB(KN / 16, QN / 16, B_);
    score_kernel<<<gB, 256, 0, stream>>>(qs, ks, wv, lens, acc);

    dim3 gC(QN / 16, B_);
    softmax_pv_kernel<<<gC, 256, 0, stream>>>(acc, values, lens, out);
}

// Round 2
// 102.940 us; speedup vs baseline: 1.2085x; 1.2085x over previous
//
#include <hip/hip_runtime.h>

#define B_ 16
#define QN 256
#define KN 256
#define DN 256
#define HN 256

#define LOG2E 1.4426950408889634f
#define TWOLOG2E 2.8853900817779268f  // exp2(x*this) = e^{2x}

// ---------------- Kernel A (fused): Y[r][h] = (sum_d X[r][d]*W[d][h]) * scale --------
// 8 rows per block; first half of grid does queries@Wq, second half keys@Wk.
__global__ __launch_bounds__(256) void proj_kernel(const float* __restrict__ Xq,
                                                   const float* __restrict__ Xk,
                                                   const float* __restrict__ Wq,
                                                   const float* __restrict__ Wk,
                                                   float* __restrict__ Yq,
                                                   float* __restrict__ Yk,
                                                   float scale) {
    const int nb = (int)gridDim.x >> 1;
    int blk = blockIdx.x;
    const float* X;
    const float* W;
    float* Y;
    if (blk < nb) { X = Xq; W = Wq; Y = Yq; }
    else          { X = Xk; W = Wk; Y = Yk; blk -= nb; }
    const int row0 = blk * 8;

    __shared__ float xl[8][DN];
    const int tid = threadIdx.x;

    // stage 8 rows = 512 float4
    {
        const float4* src = (const float4*)(X + (size_t)row0 * DN);
        float4* dst = (float4*)&xl[0][0];
        dst[tid] = src[tid];
        dst[tid + 256] = src[tid + 256];
    }
    __syncthreads();

    const int h = tid;
    float acc[8];
#pragma unroll
    for (int r = 0; r < 8; ++r) acc[r] = 0.f;

    for (int d0 = 0; d0 < DN; d0 += 4) {
        float w0 = W[(size_t)(d0 + 0) * HN + h];
        float w1 = W[(size_t)(d0 + 1) * HN + h];
        float w2 = W[(size_t)(d0 + 2) * HN + h];
        float w3 = W[(size_t)(d0 + 3) * HN + h];
#pragma unroll
        for (int r = 0; r < 8; ++r) {
            float4 x = *(const float4*)&xl[r][d0];  // wave-uniform -> LDS broadcast
            acc[r] = fmaf(x.x, w0, acc[r]);
            acc[r] = fmaf(x.y, w1, acc[r]);
            acc[r] = fmaf(x.z, w2, acc[r]);
            acc[r] = fmaf(x.w, w3, acc[r]);
        }
    }
#pragma unroll
    for (int r = 0; r < 8; ++r)
        Y[(size_t)(row0 + r) * HN + h] = acc[r] * scale;
}

// ------------- Kernel B: ACC[b][q][k] = sum_h wv[h] * rcp(1 + exp2(qs+ks)) -----------
// true score = Wsum - 2*ACC; Wsum constant per q-row -> softmax-invariant, never formed.
// Tile: 16 q x 64 k per block; thread owns 1 q x 4 k; H chunked by 64.
__global__ __launch_bounds__(256) void score_kernel(const float* __restrict__ QS,
                                                    const float* __restrict__ KS,
                                                    const float* __restrict__ wv,
                                                    const int* __restrict__ lens,
                                                    float* __restrict__ ACC) {
    const int b = blockIdx.z;
    const int k0 = blockIdx.x * 64;
    const int q0 = blockIdx.y * 16;
    const int len = lens[b];
    if (k0 >= len) return;  // whole tile masked -> never read downstream

    __shared__ float qs_l[16][65];  // stride 65: all tiled reads <=2-way (free)
    __shared__ float ks_l[64][65];
    __shared__ float wv_l[64];

    const int tid = threadIdx.x;
    const int q = tid >> 4;    // 0..15
    const int kg = tid & 15;   // owns k rows 4*kg .. 4*kg+3

    float acc[4];
#pragma unroll
    for (int t = 0; t < 4; ++t) acc[t] = 0.f;

    const float* qbase = QS + ((size_t)b * QN + q0) * HN;
    const float* kbase = KS + ((size_t)b * KN + k0) * HN;

    const int r16 = tid >> 4;
    const int c4 = (tid & 15) << 2;

    for (int h0 = 0; h0 < HN; h0 += 64) {
        *(float4*)&qs_l[r16][c4] = *(const float4*)&qbase[(size_t)r16 * HN + h0 + c4];
#pragma unroll
        for (int t = 0; t < 4; ++t) {
            int rr = r16 + (t << 4);
            *(float4*)&ks_l[rr][c4] = *(const float4*)&kbase[(size_t)rr * HN + h0 + c4];
        }
        if (tid < 16) *(float4*)&wv_l[tid << 2] = *(const float4*)&wv[h0 + (tid << 2)];
        __syncthreads();

#pragma unroll
        for (int hq = 0; hq < 64; hq += 4) {
            float4 a = *(const float4*)&qs_l[q][hq];
            float4 w = *(const float4*)&wv_l[hq];
#pragma unroll
            for (int t = 0; t < 4; ++t) {
                float4 c = *(const float4*)&ks_l[(kg << 2) + t][hq];
                float e0 = __builtin_amdgcn_exp2f(a.x + c.x);
                float e1 = __builtin_amdgcn_exp2f(a.y + c.y);
                float e2 = __builtin_amdgcn_exp2f(a.z + c.z);
                float e3 = __builtin_amdgcn_exp2f(a.w + c.w);
                acc[t] = fmaf(w.x, __builtin_amdgcn_rcpf(1.f + e0), acc[t]);
                acc[t] = fmaf(w.y, __builtin_amdgcn_rcpf(1.f + e1), acc[t]);
                acc[t] = fmaf(w.z, __builtin_amdgcn_rcpf(1.f + e2), acc[t]);
                acc[t] = fmaf(w.w, __builtin_amdgcn_rcpf(1.f + e3), acc[t]);
            }
        }
        __syncthreads();
    }

    float4 o = make_float4(acc[0], acc[1], acc[2], acc[3]);
    *(float4*)&ACC[((size_t)b * QN + q0 + q) * KN + k0 + (kg << 2)] = o;
}

// ------------- Kernel C: masked softmax over (-2*ACC) then attn @ values -------------
// 8 q-rows per block.
__global__ __launch_bounds__(256) void softmax_pv_kernel(const float* __restrict__ ACC,
                                                         const float* __restrict__ V,
                                                         const int* __restrict__ lens,
                                                         float* __restrict__ OUT) {
    const int b = blockIdx.y;
    const int q0 = blockIdx.x * 8;
    const int len = lens[b];

    __shared__ float sl[8][256];
    const int tid = threadIdx.x;

    const float* src = ACC + ((size_t)b * QN + q0) * KN;
#pragma unroll
    for (int i = tid; i < 8 * 256; i += 256) {
        int r = i >> 8, k = i & 255;
        float v = src[r * KN + k];
        sl[r][k] = (k < len) ? (-2.f * v) : -1e6f;
    }
    __syncthreads();

    // wave-parallel row softmax: wave w handles rows w, w+4
    const int wave = tid >> 6, lane = tid & 63;
    for (int r = wave; r < 8; r += 4) {
        float x0 = sl[r][lane];
        float x1 = sl[r][lane + 64];
        float x2 = sl[r][lane + 128];
        float x3 = sl[r][lane + 192];
        float m = fmaxf(fmaxf(x0, x1), fmaxf(x2, x3));
#pragma unroll
        for (int off = 32; off; off >>= 1) m = fmaxf(m, __shfl_xor(m, off, 64));
        float p0 = __builtin_amdgcn_exp2f((x0 - m) * LOG2E);
        float p1 = __builtin_amdgcn_exp2f((x1 - m) * LOG2E);
        float p2 = __builtin_amdgcn_exp2f((x2 - m) * LOG2E);
        float p3 = __builtin_amdgcn_exp2f((x3 - m) * LOG2E);
        float s = (p0 + p1) + (p2 + p3);
#pragma unroll
        for (int off = 32; off; off >>= 1) s += __shfl_xor(s, off, 64);
        float inv = 1.f / s;
        sl[r][lane] = p0 * inv;
        sl[r][lane + 64] = p1 * inv;
        sl[r][lane + 128] = p2 * inv;
        sl[r][lane + 192] = p3 * inv;
    }
    __syncthreads();

    // PV: thread owns column d; masked attn entries are exactly 0
    const int d = tid;
    float out_acc[8];
#pragma unroll
    for (int r = 0; r < 8; ++r) out_acc[r] = 0.f;

    const float* vbase = V + (size_t)b * KN * DN + d;
    const int len4 = (len + 3) & ~3;
    for (int k = 0; k < len4; k += 4) {
        float v0 = vbase[(size_t)(k + 0) * DN];
        float v1 = vbase[(size_t)(k + 1) * DN];
        float v2 = vbase[(size_t)(k + 2) * DN];
        float v3 = vbase[(size_t)(k + 3) * DN];
#pragma unroll
        for (int r = 0; r < 8; ++r) {
            float4 a = *(const float4*)&sl[r][k];
            out_acc[r] = fmaf(a.x, v0, out_acc[r]);
            out_acc[r] = fmaf(a.y, v1, out_acc[r]);
            out_acc[r] = fmaf(a.z, v2, out_acc[r]);
            out_acc[r] = fmaf(a.w, v3, out_acc[r]);
        }
    }
    float* obase = OUT + ((size_t)b * QN + q0) * DN + d;
#pragma unroll
    for (int r = 0; r < 8; ++r) obase[(size_t)r * DN] = out_acc[r];
}

extern "C" void kernel_launch(void* const* d_in, const int* in_sizes, int n_in,
                              void* d_out, int out_size, void* d_ws, size_t ws_size,
                              hipStream_t stream) {
    const float* queries = (const float*)d_in[0];
    const float* keys    = (const float*)d_in[1];
    const float* values  = (const float*)d_in[2];
    const int*   lens    = (const int*)d_in[3];
    const float* Wq      = (const float*)d_in[4];
    const float* Wk      = (const float*)d_in[5];
    const float* wv      = (const float*)d_in[6];
    float* out = (float*)d_out;

    float* qs  = (float*)d_ws;                       // [B,Q,H]  4 MB
    float* ks  = qs + (size_t)B_ * QN * HN;          // [B,K,H]  4 MB
    float* acc = ks + (size_t)B_ * KN * HN;          // [B,Q,K]  4 MB

    proj_kernel<<<(B_ * QN + B_ * KN) / 8, 256, 0, stream>>>(
        queries, keys, Wq, Wk, qs, ks, TWOLOG2E);

    dim3 gB(KN / 64, QN / 16, B_);
    score_kernel<<<gB, 256, 0, stream>>>(qs, ks, wv, lens, acc);

    dim3 gC(QN / 8, B_);
    softmax_pv_kernel<<<gC, 256, 0, stream>>>(acc, values, lens, out);
}

// Round 3
// 101.464 us; speedup vs baseline: 1.2260x; 1.0145x over previous
//
#include <hip/hip_runtime.h>

#define B_ 16
#define QN 256
#define KN 256
#define DN 256
#define HN 256

#define LOG2E 1.4426950408889634f
#define TWOLOG2E 2.8853900817779268f  // exp2(x*this) = e^{2x}

// ---------------- Kernel A (fused): Y[r][h] = (sum_d X[r][d]*W[d][h]) * scale --------
// 8 rows per block; first half of grid does queries@Wq, second half keys@Wk.
__global__ __launch_bounds__(256) void proj_kernel(const float* __restrict__ Xq,
                                                   const float* __restrict__ Xk,
                                                   const float* __restrict__ Wq,
                                                   const float* __restrict__ Wk,
                                                   float* __restrict__ Yq,
                                                   float* __restrict__ Yk,
                                                   float scale) {
    const int nb = (int)gridDim.x >> 1;
    int blk = blockIdx.x;
    const float* X;
    const float* W;
    float* Y;
    if (blk < nb) { X = Xq; W = Wq; Y = Yq; }
    else          { X = Xk; W = Wk; Y = Yk; blk -= nb; }
    const int row0 = blk * 8;

    __shared__ float xl[8][DN];
    const int tid = threadIdx.x;

    {
        const float4* src = (const float4*)(X + (size_t)row0 * DN);
        float4* dst = (float4*)&xl[0][0];
        dst[tid] = src[tid];
        dst[tid + 256] = src[tid + 256];
    }
    __syncthreads();

    const int h = tid;
    float acc[8];
#pragma unroll
    for (int r = 0; r < 8; ++r) acc[r] = 0.f;

    for (int d0 = 0; d0 < DN; d0 += 4) {
        float w0 = W[(size_t)(d0 + 0) * HN + h];
        float w1 = W[(size_t)(d0 + 1) * HN + h];
        float w2 = W[(size_t)(d0 + 2) * HN + h];
        float w3 = W[(size_t)(d0 + 3) * HN + h];
#pragma unroll
        for (int r = 0; r < 8; ++r) {
            float4 x = *(const float4*)&xl[r][d0];  // wave-uniform -> LDS broadcast
            acc[r] = fmaf(x.x, w0, acc[r]);
            acc[r] = fmaf(x.y, w1, acc[r]);
            acc[r] = fmaf(x.z, w2, acc[r]);
            acc[r] = fmaf(x.w, w3, acc[r]);
        }
    }
#pragma unroll
    for (int r = 0; r < 8; ++r)
        Y[(size_t)(row0 + r) * HN + h] = acc[r] * scale;
}

// ------------- Kernel B: ACC[b][q][k] = sum_h wv[h] * rcp(1 + exp2(qs+ks)) -----------
// true score = Wsum - 2*ACC; Wsum constant -> softmax-invariant, never formed.
// Tile 16q x 64k; thread owns 1q x 4 consecutive k; K staged TRANSPOSED in LDS so the
// inner-loop k-read is lane-consecutive float4 (conflict-free); q/wv reads broadcast.
__global__ __launch_bounds__(256) void score_kernel(const float* __restrict__ QS,
                                                    const float* __restrict__ KS,
                                                    const float* __restrict__ wv,
                                                    const int* __restrict__ lens,
                                                    float* __restrict__ ACC) {
    const int b = blockIdx.z;
    const int k0 = blockIdx.x * 64;
    const int q0 = blockIdx.y * 16;
    const int len = lens[b];
    if (k0 >= len) return;  // whole tile masked -> never read downstream

    __shared__ float qs_l[16][68];   // stride 68: 16B-aligned rows; reads are broadcast
    __shared__ float ksT[64][68];    // TRANSPOSED: ksT[h][k]; inner read lane-consecutive
    __shared__ float wv_l[64];

    const int tid = threadIdx.x;
    const int q = tid >> 4;     // 0..15
    const int kg = tid & 15;    // owns k = 4*kg .. 4*kg+3

    float acc0 = 0.f, acc1 = 0.f, acc2 = 0.f, acc3 = 0.f;

    const float* qbase = QS + ((size_t)b * QN + q0) * HN;
    const float* kbase = KS + ((size_t)b * KN + k0) * HN;

    const int sr = tid >> 4, sc4 = (tid & 15) << 2;   // qs staging coords
    const int kk = tid >> 2, kp = (tid & 3) << 4;     // ksT staging: k row, h-part

    for (int h0 = 0; h0 < HN; h0 += 64) {
        *(float4*)&qs_l[sr][sc4] = *(const float4*)&qbase[(size_t)sr * HN + h0 + sc4];
#pragma unroll
        for (int j = 0; j < 4; ++j) {
            float4 v = *(const float4*)&kbase[(size_t)kk * HN + h0 + kp + 4 * j];
            ksT[kp + 4 * j + 0][kk] = v.x;
            ksT[kp + 4 * j + 1][kk] = v.y;
            ksT[kp + 4 * j + 2][kk] = v.z;
            ksT[kp + 4 * j + 3][kk] = v.w;
        }
        if (tid < 16) *(float4*)&wv_l[tid << 2] = *(const float4*)&wv[h0 + (tid << 2)];
        __syncthreads();

#pragma unroll 8
        for (int h = 0; h < 64; ++h) {
            float qv = qs_l[q][h];                       // broadcast
            float w = wv_l[h];                           // broadcast
            float4 kv = *(const float4*)&ksT[h][kg << 2];  // lane-consecutive
            float e0 = __builtin_amdgcn_exp2f(qv + kv.x);
            float e1 = __builtin_amdgcn_exp2f(qv + kv.y);
            float e2 = __builtin_amdgcn_exp2f(qv + kv.z);
            float e3 = __builtin_amdgcn_exp2f(qv + kv.w);
            acc0 = fmaf(w, __builtin_amdgcn_rcpf(1.f + e0), acc0);
            acc1 = fmaf(w, __builtin_amdgcn_rcpf(1.f + e1), acc1);
            acc2 = fmaf(w, __builtin_amdgcn_rcpf(1.f + e2), acc2);
            acc3 = fmaf(w, __builtin_amdgcn_rcpf(1.f + e3), acc3);
        }
        __syncthreads();
    }

    *(float4*)&ACC[((size_t)b * QN + q0 + q) * KN + k0 + (kg << 2)] =
        make_float4(acc0, acc1, acc2, acc3);
}

// ------------- Kernel C: masked softmax over (-2*ACC) then attn @ values -------------
__global__ __launch_bounds__(256) void softmax_pv_kernel(const float* __restrict__ ACC,
                                                         const float* __restrict__ V,
                                                         const int* __restrict__ lens,
                                                         float* __restrict__ OUT) {
    const int b = blockIdx.y;
    const int q0 = blockIdx.x * 8;
    const int len = lens[b];

    __shared__ float sl[8][256];
    const int tid = threadIdx.x;

    const float* src = ACC + ((size_t)b * QN + q0) * KN;
#pragma unroll
    for (int i = tid; i < 8 * 256; i += 256) {
        int r = i >> 8, k = i & 255;
        float v = src[r * KN + k];
        sl[r][k] = (k < len) ? (-2.f * v) : -1e6f;
    }
    __syncthreads();

    const int wave = tid >> 6, lane = tid & 63;
    for (int r = wave; r < 8; r += 4) {
        float x0 = sl[r][lane];
        float x1 = sl[r][lane + 64];
        float x2 = sl[r][lane + 128];
        float x3 = sl[r][lane + 192];
        float m = fmaxf(fmaxf(x0, x1), fmaxf(x2, x3));
#pragma unroll
        for (int off = 32; off; off >>= 1) m = fmaxf(m, __shfl_xor(m, off, 64));
        float p0 = __builtin_amdgcn_exp2f((x0 - m) * LOG2E);
        float p1 = __builtin_amdgcn_exp2f((x1 - m) * LOG2E);
        float p2 = __builtin_amdgcn_exp2f((x2 - m) * LOG2E);
        float p3 = __builtin_amdgcn_exp2f((x3 - m) * LOG2E);
        float s = (p0 + p1) + (p2 + p3);
#pragma unroll
        for (int off = 32; off; off >>= 1) s += __shfl_xor(s, off, 64);
        float inv = 1.f / s;
        sl[r][lane] = p0 * inv;
        sl[r][lane + 64] = p1 * inv;
        sl[r][lane + 128] = p2 * inv;
        sl[r][lane + 192] = p3 * inv;
    }
    __syncthreads();

    const int d = tid;
    float out_acc[8];
#pragma unroll
    for (int r = 0; r < 8; ++r) out_acc[r] = 0.f;

    const float* vbase = V + (size_t)b * KN * DN + d;
    const int len4 = (len + 3) & ~3;
    for (int k = 0; k < len4; k += 4) {
        float v0 = vbase[(size_t)(k + 0) * DN];
        float v1 = vbase[(size_t)(k + 1) * DN];
        float v2 = vbase[(size_t)(k + 2) * DN];
        float v3 = vbase[(size_t)(k + 3) * DN];
#pragma unroll
        for (int r = 0; r < 8; ++r) {
            float4 a = *(const float4*)&sl[r][k];
            out_acc[r] = fmaf(a.x, v0, out_acc[r]);
            out_acc[r] = fmaf(a.y, v1, out_acc[r]);
            out_acc[r] = fmaf(a.z, v2, out_acc[r]);
            out_acc[r] = fmaf(a.w, v3, out_acc[r]);
        }
    }
    float* obase = OUT + ((size_t)b * QN + q0) * DN + d;
#pragma unroll
    for (int r = 0; r < 8; ++r) obase[(size_t)r * DN] = out_acc[r];
}

extern "C" void kernel_launch(void* const* d_in, const int* in_sizes, int n_in,
                              void* d_out, int out_size, void* d_ws, size_t ws_size,
                              hipStream_t stream) {
    const float* queries = (const float*)d_in[0];
    const float* keys    = (const float*)d_in[1];
    const float* values  = (const float*)d_in[2];
    const int*   lens    = (const int*)d_in[3];
    const float* Wq      = (const float*)d_in[4];
    const float* Wk      = (const float*)d_in[5];
    const float* wv      = (const float*)d_in[6];
    float* out = (float*)d_out;

    float* qs  = (float*)d_ws;                       // [B,Q,H]  4 MB
    float* ks  = qs + (size_t)B_ * QN * HN;          // [B,K,H]  4 MB
    float* acc = ks + (size_t)B_ * KN * HN;          // [B,Q,K]  4 MB

    proj_kernel<<<(B_ * QN + B_ * KN) / 8, 256, 0, stream>>>(
        queries, keys, Wq, Wk, qs, ks, TWOLOG2E);

    dim3 gB(KN / 64, QN / 16, B_);
    score_kernel<<<gB, 256, 0, stream>>>(qs, ks, wv, lens, acc);

    dim3 gC(QN / 8, B_);
    softmax_pv_kernel<<<gC, 256, 0, stream>>>(acc, values, lens, out);
}